// Round 4
// 136.834 us; speedup vs baseline: 1.0118x; 1.0118x over previous
//
#include <hip/hip_runtime.h>
#include <stdint.h>

#define N_CODES 65536
#define CB_DIM 8
#define B_ROWS 16
#define X_COLS 2048
#define M_ROWS 4096            // 16*2048/8
#define RPB 8                  // rows per block in argmin kernel
#define THREADS 256

// workspace byte offsets (all 16B-aligned) — round-0 layout, known good
#define WS_SCALE 0             // 16 f32
#define WS_IDX   256           // 4096 i32
#define WS_U     16640         // 32768 f32  (u = x/scale, flat)
#define WS_SUMS  147712        // 65536*8 f32
#define WS_CNT   2244864       // 65536 f32

// distance + min-track for one code against 8 rows. nu[] is wave-uniform
// (see below) -> lives in SGPRs: v_fma_f32 vD, sNU, vC, vD (1 sgpr src, legal).
// fma order identical to the round-0 passing kernel -> bit-identical argmin.
#define CODE_BODY(C0, C1, NIDX)                                            \
    {                                                                      \
        float hn = (C0).x * (C0).x;                                        \
        hn = fmaf((C0).y, (C0).y, hn);                                     \
        hn = fmaf((C0).z, (C0).z, hn);                                     \
        hn = fmaf((C0).w, (C0).w, hn);                                     \
        hn = fmaf((C1).x, (C1).x, hn);                                     \
        hn = fmaf((C1).y, (C1).y, hn);                                     \
        hn = fmaf((C1).z, (C1).z, hn);                                     \
        hn = fmaf((C1).w, (C1).w, hn);                                     \
        _Pragma("unroll")                                                  \
        for (int r = 0; r < RPB; r++) {                                    \
            float d = hn;                                                  \
            d = fmaf(nu[r * 8 + 0], (C0).x, d);                            \
            d = fmaf(nu[r * 8 + 1], (C0).y, d);                            \
            d = fmaf(nu[r * 8 + 2], (C0).z, d);                            \
            d = fmaf(nu[r * 8 + 3], (C0).w, d);                            \
            d = fmaf(nu[r * 8 + 4], (C1).x, d);                            \
            d = fmaf(nu[r * 8 + 5], (C1).y, d);                            \
            d = fmaf(nu[r * 8 + 6], (C1).z, d);                            \
            d = fmaf(nu[r * 8 + 7], (C1).w, d);                            \
            if (d < best[r]) { best[r] = d; bidx[r] = (NIDX); }            \
        }                                                                  \
    }

// ---------------- fused: scale + argmin + zero-selected (round-0 structure) ----------------
__global__ __launch_bounds__(256, 2) void argmin_kernel(const float* __restrict__ x,
                                                        const float* __restrict__ cb,
                                                        float* __restrict__ scale_out,
                                                        int* __restrict__ indices,
                                                        float* __restrict__ uout,
                                                        float* __restrict__ sums,
                                                        float* __restrict__ counts) {
    int tid = threadIdx.x;
    int m0 = blockIdx.x * RPB;
    int xr = m0 >> 8;                                  // this block's x row

    // ---- per-block scale for x-row xr: mean(|x[xr,:]|) ----
    const float4* xv = (const float4*)(x + xr * X_COLS);
    float4 q0 = xv[tid];
    float4 q1 = xv[tid + 256];
    float s = fabsf(q0.x) + fabsf(q0.y) + fabsf(q0.z) + fabsf(q0.w)
            + fabsf(q1.x) + fabsf(q1.y) + fabsf(q1.z) + fabsf(q1.w);
    #pragma unroll
    for (int off = 32; off > 0; off >>= 1) s += __shfl_down(s, off, 64);
    __shared__ float ls[4];
    __shared__ float scale_sh;
    int wave = tid >> 6, lane = tid & 63;
    if (lane == 0) ls[wave] = s;
    __syncthreads();
    if (tid == 0) {
        float t = (ls[0] + ls[1] + ls[2] + ls[3]) * (1.0f / (float)X_COLS);
        scale_sh = t;
        if ((blockIdx.x & 31) == 0) scale_out[xr] = t;
    }
    __syncthreads();
    float scale = scale_sh;

    // ---- u for this block's 8 rows (64 consecutive x elements) ----
    __shared__ float u_sh[RPB * CB_DIM];
    if (tid < RPB * CB_DIM) {
        int col = (m0 & 255) * CB_DIM + tid;
        float u = x[xr * X_COLS + col] / scale;
        u_sh[tid] = u;
        uout[m0 * CB_DIM + tid] = u;
    }
    __syncthreads();

    // -2u is WAVE-UNIFORM. History of this one line:
    //   round-0: asm("+v") pin -> forced into VGPR file -> allocator demoted
    //            to AGPRs -> accvgpr_read per use -> ~2x VALU (86 vs ~43 us).
    //   round-3: asm("=s" readfirstlane) x64 -> over SGPR budget -> silently
    //            wrong results (inline-asm SGPR defs under spill pressure).
    // Now: the compiler-understood convergent intrinsic. Uniform result ->
    // SGPR allocation; convergent -> not rematerialized per use; if pressure
    // exceeds budget the allocator spills CORRECTLY.
    float nu[RPB * CB_DIM];
    #pragma unroll
    for (int i = 0; i < RPB * CB_DIM; i++) {
        float v = -2.0f * u_sh[i];
        nu[i] = __uint_as_float(__builtin_amdgcn_readfirstlane(__float_as_uint(v)));
    }

    float best[RPB];
    int   bidx[RPB];
    #pragma unroll
    for (int r = 0; r < RPB; r++) { best[r] = 3.4e38f; bidx[r] = 0; }

    // ---- hot loop: 2 codes/iter, register double-prefetch, peeled tail ----
    // (round-0 structure verbatim; 128 iterations total, prefetch in range)
    const float4* cp = (const float4*)cb;
    float4 a0 = cp[2 * tid],             a1 = cp[2 * tid + 1];
    float4 b0 = cp[2 * (tid + THREADS)], b1 = cp[2 * (tid + THREADS) + 1];

    int n = tid;
    for (int k = 0; k < 127; k++, n += 2 * THREADS) {
        float4 pa0 = cp[2 * (n + 2 * THREADS)], pa1 = cp[2 * (n + 2 * THREADS) + 1];
        CODE_BODY(a0, a1, n)
        float4 pb0 = cp[2 * (n + 3 * THREADS)], pb1 = cp[2 * (n + 3 * THREADS) + 1];
        CODE_BODY(b0, b1, n + THREADS)
        a0 = pa0; a1 = pa1; b0 = pb0; b1 = pb1;
    }
    CODE_BODY(a0, a1, n)
    CODE_BODY(b0, b1, n + THREADS)

    // ---- cross-thread reduce: (sortable(dist)<<32)|idx, u64-min ----
    __shared__ unsigned long long red[RPB][THREADS];   // 16 KB
    #pragma unroll
    for (int r = 0; r < RPB; r++) {
        unsigned int b = __float_as_uint(best[r]);
        unsigned int k = b ^ ((unsigned int)((int)b >> 31) | 0x80000000u);
        red[r][tid] = ((unsigned long long)k << 32) | (unsigned int)bidx[r];
    }
    for (int t = THREADS / 2; t > 0; t >>= 1) {
        __syncthreads();
        if (tid < t) {
            #pragma unroll
            for (int r = 0; r < RPB; r++) {
                unsigned long long a = red[r][tid], c = red[r][tid + t];
                if (c < a) red[r][tid] = c;
            }
        }
    }
    __syncthreads();

    // indices + zero sums/counts at selected codes (kernel boundary orders
    // the zeros before accum; duplicate zero-writes are benign)
    if (tid < RPB) {
        int idx = (int)(red[tid][0] & 0xFFFFFFFFull);
        indices[m0 + tid] = idx;
        counts[idx] = 0.f;
        float4 z = make_float4(0.f, 0.f, 0.f, 0.f);
        float4* sp = (float4*)(sums + (size_t)idx * CB_DIM);
        sp[0] = z;
        sp[1] = z;
    }
}

// ---------------- segment-sum via atomics (wide: 128 blocks, 1 thr/(m,k)) ----------------
// Round-0 ran this on 16 blocks = 16 of 256 CUs, latency-bound (~25 us of the
// 52 us non-argmin time). Per-element decomposition is trivially equivalent.
__global__ __launch_bounds__(256) void accum_kernel(const int* __restrict__ indices,
                                                    const float* __restrict__ u,
                                                    float* __restrict__ sums,
                                                    float* __restrict__ counts) {
    int e = blockIdx.x * blockDim.x + threadIdx.x;     // 0..32767, one per (m,k)
    int m = e >> 3, k = e & 7;
    int idx = indices[m];
    if (k == 0) atomicAdd(&counts[idx], 1.0f);
    atomicAdd(&sums[(size_t)idx * CB_DIM + k], u[e]);
}

// ---------------- gather + rescale ----------------
__global__ __launch_bounds__(256) void gather_kernel(const int* __restrict__ indices,
                                                     const float* __restrict__ sums,
                                                     const float* __restrict__ counts,
                                                     const float* __restrict__ scale,
                                                     float* __restrict__ out) {
    int e = blockIdx.x * blockDim.x + threadIdx.x;     // 0..32767
    if (e < B_ROWS * X_COLS) {
        int m = e >> 3, k = e & 7;
        int idx = indices[m];
        float c = counts[idx];
        c = c < 1.f ? 1.f : c;
        out[e] = scale[e >> 11] * (sums[(size_t)idx * CB_DIM + k] / c);
    }
}

extern "C" void kernel_launch(void* const* d_in, const int* in_sizes, int n_in,
                              void* d_out, int out_size, void* d_ws, size_t ws_size,
                              hipStream_t stream) {
    const float* x  = (const float*)d_in[0];           // [16,2048]
    const float* cb = (const float*)d_in[1];           // [65536,8]
    char* ws = (char*)d_ws;
    float* scale   = (float*)(ws + WS_SCALE);
    int*   indices = (int*)(ws + WS_IDX);
    float* u       = (float*)(ws + WS_U);
    float* sums    = (float*)(ws + WS_SUMS);
    float* counts  = (float*)(ws + WS_CNT);
    float* out     = (float*)d_out;

    argmin_kernel<<<M_ROWS / RPB, 256, 0, stream>>>(x, cb, scale, indices, u, sums, counts);
    accum_kernel <<<(M_ROWS * CB_DIM) / 256, 256, 0, stream>>>(indices, u, sums, counts);
    gather_kernel<<<(B_ROWS * X_COLS) / 256, 256, 0, stream>>>(indices, sums, counts, scale, out);
}